// Round 9
// baseline (215.562 us; speedup 1.0000x reference)
//
#include <hip/hip_runtime.h>

constexpr int B = 512;
constexpr int D = 2048;
constexpr int C = 10000;
constexpr long long ND = (long long)C * D;      // 20,480,000

// ---------------------------------------------------------------------------
// K0 (tiny): zero the loss accumulator slot before the blit + group kernels.
// ---------------------------------------------------------------------------
__global__ void init_kernel(float* __restrict__ out) {
    if (threadIdx.x == 0) out[0] = 0.0f;
}

// ---------------------------------------------------------------------------
// K2: fused rank + loss + closed-form center-update for touched rows.
// One block per sample; only rank-0 blocks proceed; closed form
//   new_row = 0.5^k * c + sum_r 0.5^(k-r) * f_r      (alpha = 0.5)
// One loss atomic per group. Runs after the D2D blit (stream-ordered) and
// overwrites the touched rows the blit copied.
// ---------------------------------------------------------------------------
__global__ void group_kernel(const float* __restrict__ features,
                             const int* __restrict__ labels,
                             const float* __restrict__ centers,
                             float* __restrict__ out) {
    const int i = blockIdx.x;
    __shared__ int sl[B];
    __shared__ int mem[B];
    for (int j = threadIdx.x; j < B; j += blockDim.x) sl[j] = labels[j];
    __syncthreads();
    const int l = sl[i];

    int k = 0;
    bool rank0 = true;                           // block-uniform
    for (int j = 0; j < B; ++j) {
        if (sl[j] == l) {
            if (j < i) { rank0 = false; break; }
            mem[k++] = j;                        // uniform write
        }
    }
    if (!rank0) return;

    const float kc = exp2f(-(float)k);           // 0.5^k
    const float* __restrict__ crow = centers + (long long)l * D;
    float*       __restrict__ orow = out + 1 + (long long)l * D;
    const int tx = threadIdx.x;

    float cv[8], acc[8];
    float lsum = 0.0f;
#pragma unroll
    for (int jj = 0; jj < 8; ++jj) {
        cv[jj]  = crow[tx + jj * 256];
        acc[jj] = kc * cv[jj];
    }
    for (int r = 0; r < k; ++r) {
        const float* __restrict__ frow = features + (long long)mem[r] * D;
        const float coef = exp2f(-(float)(k - r));   // 0.5^(k-r)
#pragma unroll
        for (int jj = 0; jj < 8; ++jj) {
            float fv = frow[tx + jj * 256];
            float d  = fv - cv[jj];
            lsum    += d * d;
            acc[jj] += coef * fv;
        }
    }
#pragma unroll
    for (int jj = 0; jj < 8; ++jj) orow[tx + jj * 256] = acc[jj];

    for (int off = 32; off > 0; off >>= 1) lsum += __shfl_down(lsum, off);
    __shared__ float wsum[4];
    if ((tx & 63) == 0) wsum[tx >> 6] = lsum;
    __syncthreads();
    if (tx == 0) {
        float tot = wsum[0] + wsum[1] + wsum[2] + wsum[3];
        atomicAdd(out, tot * (1.0f / ((float)B * (float)D)));
    }
}

extern "C" void kernel_launch(void* const* d_in, const int* in_sizes, int n_in,
                              void* d_out, int out_size, void* d_ws, size_t ws_size,
                              hipStream_t stream) {
    const float* features = (const float*)d_in[0];
    const int*   labels   = (const int*)d_in[1];
    const float* centers  = (const float*)d_in[2];
    float*       out      = (float*)d_out;

    init_kernel<<<1, 64, 0, stream>>>(out);
    // AMD's own D2D copy path (blessed for graph capture by the harness):
    // out[1..ND] <- centers[0..ND-1]
    hipMemcpyAsync(out + 1, centers, (size_t)ND * sizeof(float),
                   hipMemcpyDeviceToDevice, stream);
    group_kernel<<<B, 256, 0, stream>>>(features, labels, centers, out);
}

// Round 10
// 165.203 us; speedup vs baseline: 1.3048x; 1.3048x over previous
//
#include <hip/hip_runtime.h>

constexpr int B = 512;
constexpr int D = 2048;
constexpr int C = 10000;
constexpr long long ND = (long long)C * D;      // 20,480,000
constexpr int BMW = (C + 31) / 32;              // 313 bitmap words
constexpr int NBLK = 2048;                      // all blocks copy; first B also group

// ---------------------------------------------------------------------------
// K0 (tiny): zero the loss slot BEFORE fused kernel (group blocks atomicAdd
// into out[0]; intra-kernel zeroing would race with those atomics).
// ---------------------------------------------------------------------------
__global__ void prep_kernel(float* __restrict__ out) {
    if (threadIdx.x == 0) out[0] = 0.0f;
}

// ---------------------------------------------------------------------------
// K1 (fused): blocks [0,B) do the group role (closed-form EMA update of
// touched rows + loss), then ALL blocks run the copy role over untouched rows.
//
// Copy scheme (NEW this round): ALIGNED float4 loads from centers + SPLIT
// shifted stores {dword, dwordx2, dword} into out[4m+1..4m+4]. Since D=2048
// is divisible by 4, each source float4 lies entirely in ONE center row ->
// one bitmap lookup per vector, no shfl, no lane-0 patch load, no read-side
// splits. Stores are fire-and-forget; TCC merges the partial-line writes
// (the 6.7 TB/s harness fill proves write-path headroom).
// m = M-1 writes out[ND] naturally (4(M-1)+4 = ND) -> no tail case.
// Touched-row bitmap is built per-block in LDS from labels (no d_ws).
// ---------------------------------------------------------------------------
__global__ __launch_bounds__(256) void fused_kernel(
        const float* __restrict__ features,
        const int* __restrict__ labels,
        const float* __restrict__ centers,
        float* __restrict__ out) {
    __shared__ int sl[B];
    __shared__ int mem[B];
    __shared__ unsigned int sb[BMW];
    __shared__ float wsum[4];
    const int tx  = threadIdx.x;
    const int bid = blockIdx.x;

    for (int j = tx; j < BMW; j += 256) sb[j] = 0u;
    __syncthreads();
    for (int j = tx; j < B; j += 256) {
        int l = labels[j];
        sl[j] = l;
        atomicOr(&sb[l >> 5], 1u << (l & 31));
    }
    __syncthreads();

    if (bid < B) {
        // ----------------- group role: one block per sample -----------------
        const int i = bid;
        const int l = sl[i];
        int k = 0;
        bool rank0 = true;                       // block-uniform
        for (int j = 0; j < B; ++j) {
            if (sl[j] == l) {
                if (j < i) { rank0 = false; break; }
                mem[k++] = j;                    // uniform write, benign race
            }
        }
        if (rank0) {
            const float kc = exp2f(-(float)k);   // 0.5^k
            const float* __restrict__ crow = centers + (long long)l * D;
            float*       __restrict__ orow = out + 1 + (long long)l * D;
            float cv[8], acc[8];
            float lsum = 0.0f;
#pragma unroll
            for (int jj = 0; jj < 8; ++jj) {
                cv[jj]  = crow[tx + jj * 256];
                acc[jj] = kc * cv[jj];
            }
            for (int r = 0; r < k; ++r) {
                const float* __restrict__ frow = features + (long long)mem[r] * D;
                const float coef = exp2f(-(float)(k - r));   // 0.5^(k-r)
#pragma unroll
                for (int jj = 0; jj < 8; ++jj) {
                    float fv = frow[tx + jj * 256];
                    float d  = fv - cv[jj];
                    lsum    += d * d;
                    acc[jj] += coef * fv;
                }
            }
#pragma unroll
            for (int jj = 0; jj < 8; ++jj) orow[tx + jj * 256] = acc[jj];

            for (int off = 32; off > 0; off >>= 1) lsum += __shfl_down(lsum, off);
            if ((tx & 63) == 0) wsum[tx >> 6] = lsum;
            __syncthreads();                     // uniform (rank0 is uniform)
            if (tx == 0) {
                float tot = wsum[0] + wsum[1] + wsum[2] + wsum[3];
                atomicAdd(out, tot * (1.0f / ((float)B * (float)D)));
            }
        }
    }

    // ----------------- copy role: all blocks, aligned loads + split stores ---
    const long long M = ND / 4;                  // 5,120,000 float4s
    const long long stride = (long long)NBLK * 256;
    const float4* __restrict__ src = reinterpret_cast<const float4*>(centers);

    auto store_one = [&](long long m, float4 v) {
        int r = (int)(m >> 9);                   // row of ALL 4 elems (D%4==0)
        if (!((sb[r >> 5] >> (r & 31)) & 1u)) {
            out[4 * m + 1] = v.x;
            *reinterpret_cast<float2*>(out + 4 * m + 2) = make_float2(v.y, v.z);
            out[4 * m + 4] = v.w;                // m=M-1 -> out[ND], exact end
        }
    };

    long long t = (long long)bid * 256 + tx;
    long long m = t;
    for (; m + 3 * stride < M; m += 4 * stride) {
        long long m0 = m, m1 = m + stride, m2 = m + 2 * stride, m3 = m + 3 * stride;
        float4 v0 = src[m0];                     // 4 independent aligned loads
        float4 v1 = src[m1];
        float4 v2 = src[m2];
        float4 v3 = src[m3];
        store_one(m0, v0);
        store_one(m1, v1);
        store_one(m2, v2);
        store_one(m3, v3);
    }
    for (; m < M; m += stride) {
        store_one(m, src[m]);
    }
}

extern "C" void kernel_launch(void* const* d_in, const int* in_sizes, int n_in,
                              void* d_out, int out_size, void* d_ws, size_t ws_size,
                              hipStream_t stream) {
    const float* features = (const float*)d_in[0];
    const int*   labels   = (const int*)d_in[1];
    const float* centers  = (const float*)d_in[2];
    float*       out      = (float*)d_out;

    prep_kernel<<<1, 64, 0, stream>>>(out);
    fused_kernel<<<NBLK, 256, 0, stream>>>(features, labels, centers, out);
}